// Round 2
// baseline (1648.396 us; speedup 1.0000x reference)
//
#include <hip/hip_runtime.h>

// MultilayeredNetwork: 8-step recurrent sparse net.
//   state_0 = scatter(sensory inp[:, :, 0])           (rows 0..4999, sensory_indices = arange)
//   per t:  acc = SpMM(W, state_t)  [COO, FIXED-POINT int64 atomics -> bitwise deterministic]
//           act = tanh(5 * thresh(acc))
//           t<7: state_{t+1} = min(act + inject(inp[:,:,t+1]), 1); out[:, :, t] = state_{t+1}
//           t=7:                                                   out[:, :, 7] = act
// out[b, n, t] -> b*N*T + n*T + t  (float32)

#define N_NEURONS 100000
#define NNZ_CNT   3200000
#define N_SENSORY 5000
#define BATCH     16
#define T_LAYERS  8
#define THRESH    0.01f
#define STEEP     5.0f

#define NB (N_NEURONS * BATCH)
#define NT (N_NEURONS * T_LAYERS)
#define ST (N_SENSORY * T_LAYERS)

// Fixed-point scale: multiply by 2^44 is EXACT in fp32 (exponent shift); llrintf
// quantizes each term with abs error 2^-45; int64 sum is exact & order-independent.
#define FXSCALE   17592186044416.0f        /* 2^44 */
#define FXINV     (1.0 / 17592186044416.0) /* double, exact */

__device__ __forceinline__ float thresh_clamp_inp(float u) {
    u = (u >= THRESH) ? u : 0.0f;
    return fminf(u, 1.0f);
}

__device__ __forceinline__ float activate(float y) {
    y = (y >= THRESH) ? y : 0.0f;
    return tanhf(STEEP * y);
}

// state = scattered sensory input for t=0; acc = 0 everywhere.
__global__ void k_init(const float* __restrict__ inp,
                       float* __restrict__ state,
                       long long* __restrict__ acc) {
    int stride = gridDim.x * blockDim.x;
    for (int i = blockIdx.x * blockDim.x + threadIdx.x; i < NB; i += stride) {
        int n = i >> 4, b = i & 15;
        float v = 0.0f;
        if (n < N_SENSORY) v = thresh_clamp_inp(inp[b * ST + n * T_LAYERS + 0]);
        state[i] = v;
        acc[i]   = 0LL;
    }
}

// COO SpMM: acc[r, b] += fx(vals[e] * state[c, b]).  16 lanes per edge (one per batch).
__global__ void __launch_bounds__(256) k_spmm(const float* __restrict__ vals,
                                              const int* __restrict__ rows,
                                              const int* __restrict__ cols,
                                              const float* __restrict__ state,
                                              long long* acc) {
    int tid = blockIdx.x * blockDim.x + threadIdx.x;
    int b = tid & 15;
    int e = tid >> 4;
    int estride = (gridDim.x * blockDim.x) >> 4;
    for (; e < NNZ_CNT; e += estride) {
        int   c  = cols[e];
        float xv = state[c * BATCH + b];
        float v  = vals[e];
        long long fx = llrintf(v * xv * FXSCALE);
        if (fx != 0LL) {                  // ~half of state entries are exactly 0 (thresholded)
            int r = rows[e];
            atomicAdd((unsigned long long*)&acc[r * BATCH + b],
                      (unsigned long long)fx);
        }
    }
}

// act -> inject next input -> clamp -> write state & out plane t -> clear acc.
__global__ void k_act_inject(long long* acc,               // read then cleared
                             const float* __restrict__ inp,
                             float* __restrict__ state,
                             float* __restrict__ out,
                             int t /* 0..6: out plane t, injects inp t+1 */) {
    int stride = gridDim.x * blockDim.x;
    for (int i = blockIdx.x * blockDim.x + threadIdx.x; i < NB; i += stride) {
        int n = i >> 4, b = i & 15;
        float y = (float)((double)acc[i] * FXINV);
        acc[i] = 0LL;
        float v = activate(y);
        if (n < N_SENSORY) {
            v += thresh_clamp_inp(inp[b * ST + n * T_LAYERS + (t + 1)]);
        }
        v = fminf(v, 1.0f);               // ref clamps whole vector (no-op off-sensory: tanh < 1)
        state[i] = v;
        out[b * NT + n * T_LAYERS + t] = v;
    }
}

// Final step: activation only, out plane T-1.
__global__ void k_act_final(const long long* __restrict__ acc,
                            float* __restrict__ out) {
    int stride = gridDim.x * blockDim.x;
    for (int i = blockIdx.x * blockDim.x + threadIdx.x; i < NB; i += stride) {
        int n = i >> 4, b = i & 15;
        float y = (float)((double)acc[i] * FXINV);
        out[b * NT + n * T_LAYERS + (T_LAYERS - 1)] = activate(y);
    }
}

extern "C" void kernel_launch(void* const* d_in, const int* in_sizes, int n_in,
                              void* d_out, int out_size, void* d_ws, size_t ws_size,
                              hipStream_t stream) {
    const float* inputs = (const float*)d_in[0];   // (16, 5000, 8) f32
    const float* vals   = (const float*)d_in[1];   // (3.2M,) f32
    const int*   rows   = (const int*)  d_in[2];   // (3.2M,) i32
    const int*   cols   = (const int*)  d_in[3];   // (3.2M,) i32
    // d_in[4] sensory_indices == arange(5000) by construction; used implicitly.
    float* out = (float*)d_out;

    long long* acc   = (long long*)d_ws;    // N*B i64 = 12.8 MB (8B-aligned at base)
    float*     state = (float*)(acc + NB);  // N*B f32 =  6.4 MB

    const int block   = 256;
    const int grid_ew = 2048;               // elementwise: 1.6M items, ~3 iters/thread
    const int grid_sp = 2048;               // spmm: 51.2M lane-items, ~98 edges/thread

    k_init<<<grid_ew, block, 0, stream>>>(inputs, state, acc);
    for (int t = 0; t < T_LAYERS; ++t) {
        k_spmm<<<grid_sp, block, 0, stream>>>(vals, rows, cols, state, acc);
        if (t < T_LAYERS - 1)
            k_act_inject<<<grid_ew, block, 0, stream>>>(acc, inputs, state, out, t);
        else
            k_act_final<<<grid_ew, block, 0, stream>>>(acc, out);
    }
}

// Round 3
// 1234.930 us; speedup vs baseline: 1.3348x; 1.3348x over previous
//
#include <hip/hip_runtime.h>

// MultilayeredNetwork: 8-step recurrent sparse net, CSR-per-call edition.
//   build CSR (hist + scan + fill) each call  -> no atomics in the hot loop
//   per t: plane[t][n][b] = epilogue(sum_fx over row edges of val*state[col][b])
//   final: transpose planes[t][n][b] -> out[b][n][t]
// Fixed-point int64 row accumulation (scale 2^44) => exact, order-independent,
// bitwise-deterministic across replays even though CSR fill order varies.

#define N_NEURONS 100000
#define NNZ_CNT   3200000
#define N_SENSORY 5000
#define BATCH     16
#define T_LAYERS  8
#define THRESH    0.01f
#define STEEP     5.0f

#define NB (N_NEURONS * BATCH)
#define NT (N_NEURONS * T_LAYERS)
#define ST (N_SENSORY * T_LAYERS)

#define FXSCALE   17592186044416.0f        /* 2^44: exact fp32 scale (exp shift) */
#define FXINV     (1.0 / 17592186044416.0) /* double, exact */

#define CHUNK   1024
#define NCHUNK  ((N_NEURONS + CHUNK - 1) / CHUNK)   /* 98 */

__device__ __forceinline__ float thresh_clamp_inp(float u) {
    u = (u >= THRESH) ? u : 0.0f;
    return fminf(u, 1.0f);
}
__device__ __forceinline__ float activate(float y) {
    y = (y >= THRESH) ? y : 0.0f;
    return tanhf(STEEP * y);
}

// ---------------- CSR build ----------------

// state0 (lives in planes[7] slot) + zero row counters.
__global__ void k_init(const float* __restrict__ inp, float* __restrict__ state0,
                       int* __restrict__ row_cnt) {
    int stride = gridDim.x * blockDim.x;
    for (int i = blockIdx.x * blockDim.x + threadIdx.x; i < NB; i += stride) {
        int n = i >> 4, b = i & 15;
        float v = 0.0f;
        if (n < N_SENSORY) v = thresh_clamp_inp(inp[b * ST + n * T_LAYERS + 0]);
        state0[i] = v;
        if (i < N_NEURONS) row_cnt[i] = 0;
    }
}

__global__ void k_hist(const int* __restrict__ rows, int* __restrict__ row_cnt) {
    int e = blockIdx.x * blockDim.x + threadIdx.x;
    if (e < NNZ_CNT) atomicAdd(&row_cnt[rows[e]], 1);
}

__global__ void k_scan_partial(const int* __restrict__ row_cnt, int* __restrict__ partial) {
    __shared__ int lds[256];
    int base = blockIdx.x * CHUNK + threadIdx.x * 4;
    int s = 0;
    #pragma unroll
    for (int k = 0; k < 4; ++k) {
        int idx = base + k;
        if (idx < N_NEURONS) s += row_cnt[idx];
    }
    lds[threadIdx.x] = s;
    __syncthreads();
    for (int off = 128; off > 0; off >>= 1) {
        if (threadIdx.x < off) lds[threadIdx.x] += lds[threadIdx.x + off];
        __syncthreads();
    }
    if (threadIdx.x == 0) partial[blockIdx.x] = lds[0];
}

__global__ void k_scan_offsets(int* __restrict__ partial, int* __restrict__ row_ptr) {
    __shared__ int lds[128];
    int v = (threadIdx.x < NCHUNK) ? partial[threadIdx.x] : 0;
    lds[threadIdx.x] = v;
    __syncthreads();
    for (int off = 1; off < 128; off <<= 1) {
        int add = (threadIdx.x >= off) ? lds[threadIdx.x - off] : 0;
        __syncthreads();
        lds[threadIdx.x] += add;
        __syncthreads();
    }
    if (threadIdx.x < NCHUNK) partial[threadIdx.x] = lds[threadIdx.x] - v;  // exclusive
    if (threadIdx.x == 0) row_ptr[N_NEURONS] = NNZ_CNT;
}

__global__ void k_scan_final(const int* __restrict__ row_cnt, const int* __restrict__ partial,
                             int* __restrict__ row_ptr, int* __restrict__ cursor) {
    __shared__ int lds[256];
    int base = blockIdx.x * CHUNK + threadIdx.x * 4;
    int c[4];
    int s = 0;
    #pragma unroll
    for (int k = 0; k < 4; ++k) {
        int idx = base + k;
        c[k] = (idx < N_NEURONS) ? row_cnt[idx] : 0;
        s += c[k];
    }
    lds[threadIdx.x] = s;
    __syncthreads();
    for (int off = 1; off < 256; off <<= 1) {
        int add = (threadIdx.x >= off) ? lds[threadIdx.x - off] : 0;
        __syncthreads();
        lds[threadIdx.x] += add;
        __syncthreads();
    }
    int pre = partial[blockIdx.x] + (lds[threadIdx.x] - s);  // exclusive prefix of elem 0
    #pragma unroll
    for (int k = 0; k < 4; ++k) {
        int idx = base + k;
        if (idx < N_NEURONS) {
            row_ptr[idx] = pre;
            cursor[idx]  = pre;
            pre += c[k];
        }
    }
}

__global__ void k_fill(const float* __restrict__ vals, const int* __restrict__ rows,
                       const int* __restrict__ cols, int* cursor, int2* __restrict__ packed) {
    int e = blockIdx.x * blockDim.x + threadIdx.x;
    if (e < NNZ_CNT) {
        int r   = rows[e];
        int pos = atomicAdd(&cursor[r], 1);
        packed[pos] = make_int2(cols[e], __float_as_int(vals[e]));
    }
}

// ---------------- fused per-layer SpMM + activation ----------------
// 16 lanes per row (one per batch); register fixed-point accumulate; no atomics.
__global__ void __launch_bounds__(256) k_layer(const int* __restrict__ row_ptr,
                                               const int2* __restrict__ packed,
                                               const float* __restrict__ state_in,
                                               const float* __restrict__ inp,
                                               float* __restrict__ plane_out,
                                               int t) {
    int tid = blockIdx.x * blockDim.x + threadIdx.x;
    int r = tid >> 4, b = tid & 15;
    if (r >= N_NEURONS) return;
    int s = row_ptr[r], e = row_ptr[r + 1];
    long long acc = 0;
    for (int i = s; i < e; ++i) {
        int2  pe = packed[i];                       // broadcast across the 16-lane group
        float xv = state_in[pe.x * BATCH + b];      // coalesced 64B gather per group
        float v  = __int_as_float(pe.y);
        acc += (long long)llrintf(v * xv * FXSCALE);
    }
    float y = (float)((double)acc * FXINV);
    float a = activate(y);
    if (t < T_LAYERS - 1) {
        if (r < N_SENSORY) a += thresh_clamp_inp(inp[b * ST + r * T_LAYERS + (t + 1)]);
        a = fminf(a, 1.0f);                         // off-sensory no-op (|tanh|<1)
    }
    plane_out[r * BATCH + b] = a;
}

// ---------------- planes[t][n][b] -> out[b][n][t] ----------------
__global__ void k_out(const float* __restrict__ planes, float* __restrict__ out) {
    int i = blockIdx.x * blockDim.x + threadIdx.x;   // i = n*16 + b
    if (i >= NB) return;
    int n = i >> 4, b = i & 15;
    float4 o0, o1;
    o0.x = planes[0 * NB + i]; o0.y = planes[1 * NB + i];
    o0.z = planes[2 * NB + i]; o0.w = planes[3 * NB + i];
    o1.x = planes[4 * NB + i]; o1.y = planes[5 * NB + i];
    o1.z = planes[6 * NB + i]; o1.w = planes[7 * NB + i];
    float4* dst = (float4*)&out[b * NT + n * T_LAYERS];   // 32B-aligned
    dst[0] = o0; dst[1] = o1;
}

// ---------------- fallback (round-2 atomic path, needs only 19.2 MB ws) ----------------
__global__ void k2_init(const float* __restrict__ inp, float* __restrict__ state,
                        long long* __restrict__ acc) {
    int stride = gridDim.x * blockDim.x;
    for (int i = blockIdx.x * blockDim.x + threadIdx.x; i < NB; i += stride) {
        int n = i >> 4, b = i & 15;
        float v = 0.0f;
        if (n < N_SENSORY) v = thresh_clamp_inp(inp[b * ST + n * T_LAYERS + 0]);
        state[i] = v;
        acc[i]   = 0LL;
    }
}
__global__ void __launch_bounds__(256) k2_spmm(const float* __restrict__ vals,
                                               const int* __restrict__ rows,
                                               const int* __restrict__ cols,
                                               const float* __restrict__ state,
                                               long long* acc) {
    int tid = blockIdx.x * blockDim.x + threadIdx.x;
    int b = tid & 15;
    int e = tid >> 4;
    int estride = (gridDim.x * blockDim.x) >> 4;
    for (; e < NNZ_CNT; e += estride) {
        int   c  = cols[e];
        float xv = state[c * BATCH + b];
        float v  = vals[e];
        long long fx = llrintf(v * xv * FXSCALE);
        if (fx != 0LL) {
            int r = rows[e];
            atomicAdd((unsigned long long*)&acc[r * BATCH + b], (unsigned long long)fx);
        }
    }
}
__global__ void k2_act_inject(long long* acc, const float* __restrict__ inp,
                              float* __restrict__ state, float* __restrict__ out, int t) {
    int stride = gridDim.x * blockDim.x;
    for (int i = blockIdx.x * blockDim.x + threadIdx.x; i < NB; i += stride) {
        int n = i >> 4, b = i & 15;
        float y = (float)((double)acc[i] * FXINV);
        acc[i] = 0LL;
        float v = activate(y);
        if (n < N_SENSORY) v += thresh_clamp_inp(inp[b * ST + n * T_LAYERS + (t + 1)]);
        v = fminf(v, 1.0f);
        state[i] = v;
        out[b * NT + n * T_LAYERS + t] = v;
    }
}
__global__ void k2_act_final(const long long* __restrict__ acc, float* __restrict__ out) {
    int stride = gridDim.x * blockDim.x;
    for (int i = blockIdx.x * blockDim.x + threadIdx.x; i < NB; i += stride) {
        int n = i >> 4, b = i & 15;
        float y = (float)((double)acc[i] * FXINV);
        out[b * NT + n * T_LAYERS + (T_LAYERS - 1)] = activate(y);
    }
}

extern "C" void kernel_launch(void* const* d_in, const int* in_sizes, int n_in,
                              void* d_out, int out_size, void* d_ws, size_t ws_size,
                              hipStream_t stream) {
    const float* inputs = (const float*)d_in[0];   // (16, 5000, 8) f32
    const float* vals   = (const float*)d_in[1];   // (3.2M,) f32
    const int*   rows   = (const int*)  d_in[2];   // (3.2M,) i32
    const int*   cols   = (const int*)  d_in[3];   // (3.2M,) i32
    float* out = (float*)d_out;

    // ws layout (CSR path)
    const size_t sz_planes = (size_t)T_LAYERS * NB * 4;   // 51.2 MB
    const size_t sz_packed = (size_t)NNZ_CNT * 8;         // 25.6 MB
    const size_t sz_rowptr = ((size_t)N_NEURONS + 2) * 4;
    const size_t sz_cursor = (size_t)N_NEURONS * 4;
    const size_t sz_part   = 512;
    const size_t REQ = sz_planes + sz_packed + sz_rowptr + sz_cursor + sz_part;

    const int block = 256;

    if (ws_size >= REQ) {
        char* ws = (char*)d_ws;
        float* planes  = (float*)ws;
        int2*  packed  = (int2*)(ws + sz_planes);
        int*   row_ptr = (int*)(ws + sz_planes + sz_packed);
        int*   cursor  = (int*)(ws + sz_planes + sz_packed + sz_rowptr);
        int*   partial = (int*)(ws + sz_planes + sz_packed + sz_rowptr + sz_cursor);
        float* state0  = planes + (size_t)(T_LAYERS - 1) * NB;  // planes[7] slot, consumed by layer 0
        int*   row_cnt = cursor;                                 // reuse: counts then cursors

        const int grid_nb  = (NB + block - 1) / block;           // 6250
        const int grid_nnz = (NNZ_CNT + block - 1) / block;      // 12500

        k_init<<<grid_nb, block, 0, stream>>>(inputs, state0, row_cnt);
        k_hist<<<grid_nnz, block, 0, stream>>>(rows, row_cnt);
        k_scan_partial<<<NCHUNK, 256, 0, stream>>>(row_cnt, partial);
        k_scan_offsets<<<1, 128, 0, stream>>>(partial, row_ptr);
        k_scan_final<<<NCHUNK, 256, 0, stream>>>(row_cnt, partial, row_ptr, cursor);
        k_fill<<<grid_nnz, block, 0, stream>>>(vals, rows, cols, cursor, packed);

        for (int t = 0; t < T_LAYERS; ++t) {
            const float* sin_ = (t == 0) ? state0 : planes + (size_t)(t - 1) * NB;
            k_layer<<<grid_nb, block, 0, stream>>>(row_ptr, packed, sin_, inputs,
                                                   planes + (size_t)t * NB, t);
        }
        k_out<<<grid_nb, block, 0, stream>>>(planes, out);
    } else {
        // fallback: round-2 atomic path (19.2 MB ws)
        long long* acc   = (long long*)d_ws;
        float*     state = (float*)(acc + NB);
        const int grid_ew = 2048, grid_sp = 2048;
        k2_init<<<grid_ew, block, 0, stream>>>(inputs, state, acc);
        for (int t = 0; t < T_LAYERS; ++t) {
            k2_spmm<<<grid_sp, block, 0, stream>>>(vals, rows, cols, state, acc);
            if (t < T_LAYERS - 1)
                k2_act_inject<<<grid_ew, block, 0, stream>>>(acc, inputs, state, out, t);
            else
                k2_act_final<<<grid_ew, block, 0, stream>>>(acc, out);
        }
    }
}